// Round 4
// baseline (1028.702 us; speedup 1.0000x reference)
//
#include <hip/hip_runtime.h>

#define DEG 16
#define MAX_ITERS 32
#define BLK_F 1024
#define GRID_F 256

// ===========================================================================
// Lightweight grid barrier: one atomic arrival per block, monotone generation
// counter (no sense reversal). Spin is a relaxed agent-scope load with
// s_sleep backoff. Requires *cnt == *gen == 0 at kernel start.
// ===========================================================================
__device__ __forceinline__ void grid_barrier(unsigned* cnt, unsigned* gen,
                                             unsigned target, unsigned nblocks) {
    __syncthreads();
    if (threadIdx.x == 0) {
        __threadfence();                  // release
        unsigned arrived = __hip_atomic_fetch_add(cnt, 1u, __ATOMIC_ACQ_REL,
                                                  __HIP_MEMORY_SCOPE_AGENT);
        if (arrived == nblocks - 1u) {
            __hip_atomic_store(cnt, 0u, __ATOMIC_RELAXED, __HIP_MEMORY_SCOPE_AGENT);
            __hip_atomic_fetch_add(gen, 1u, __ATOMIC_RELEASE, __HIP_MEMORY_SCOPE_AGENT);
        } else {
            while (__hip_atomic_load(gen, __ATOMIC_RELAXED,
                                     __HIP_MEMORY_SCOPE_AGENT) < target) {
                __builtin_amdgcn_s_sleep(2);    // ~128 cyc between polls
            }
        }
        __threadfence();                  // acquire
    }
    __syncthreads();
}

__device__ __forceinline__ void softmax_row(const float* __restrict__ fp,
                                            const int* __restrict__ adj,
                                            float* __restrict__ wout,
                                            size_t base, int N) {
    const float4* f4 = (const float4*)(fp + base);
    const int4*   a4 = (const int4*)(adj + base);
    float v[DEG];
#pragma unroll
    for (int k = 0; k < DEG / 4; ++k) {
        float4 f = f4[k];
        int4   a = a4[k];
        v[4*k+0] = (a.x == N) ? f.x - 1e7f : f.x;
        v[4*k+1] = (a.y == N) ? f.y - 1e7f : f.y;
        v[4*k+2] = (a.z == N) ? f.z - 1e7f : f.z;
        v[4*k+3] = (a.w == N) ? f.w - 1e7f : f.w;
    }
    float m = v[0];
#pragma unroll
    for (int j = 1; j < DEG; ++j) m = fmaxf(m, v[j]);
    float s = 0.f;
#pragma unroll
    for (int j = 0; j < DEG; ++j) { v[j] = __expf(v[j] - m); s += v[j]; }
    float inv = 1.f / s;
    float4* w4 = (float4*)(wout + base);
#pragma unroll
    for (int k = 0; k < DEG / 4; ++k) {
        float4 o;
        o.x = v[4*k+0] * inv;
        o.y = v[4*k+1] * inv;
        o.z = v[4*k+2] * inv;
        o.w = v[4*k+3] * inv;
        w4[k] = o;
    }
}

// gather one node's 16 (src, w) pairs using int4 loads of in_idx
__device__ __forceinline__ void load_edges(const int* __restrict__ in_idx,
                                           const float* __restrict__ wsrc,
                                           int n, int N,
                                           int* __restrict__ src,
                                           float* __restrict__ w) {
    const int4* t4 = (const int4*)(in_idx + 3 * (size_t)n * DEG);
#pragma unroll
    for (int g = 0; g < 4; ++g) {
        int4 qa = t4[3*g + 0];
        int4 qb = t4[3*g + 1];
        int4 qc = t4[3*g + 2];
        int b0 = qa.x, s0 = qa.y, l0 = qa.z;
        int b1 = qa.w, s1 = qb.x, l1 = qb.y;
        int b2 = qb.z, s2 = qb.w, l2 = qc.x;
        int b3 = qc.y, s3 = qc.z, l3 = qc.w;
        int f0 = b0 * N + s0, f1 = b1 * N + s1;
        int f2 = b2 * N + s2, f3 = b3 * N + s3;
        src[4*g+0] = f0; src[4*g+1] = f1; src[4*g+2] = f2; src[4*g+3] = f3;
        w[4*g+0] = wsrc[(size_t)f0 * DEG + l0];   // padded -> exactly 0.0f
        w[4*g+1] = wsrc[(size_t)f1 * DEG + l1];
        w[4*g+2] = wsrc[(size_t)f2 * DEG + l2];
        w[4*g+3] = wsrc[(size_t)f3 * DEG + l3];
    }
}

// ===========================================================================
// FUSED PATH v3: 256 blocks x 1024 threads — one block per CU, exact per-CU
// load balance (each block owns a contiguous chunk of ceil(nodes/256) nodes),
// XCD-batch affinity so each XCD's L2 gathers only from its batch's 400 KB
// R segment. Edge tables in registers; padded slots skipped wave-uniformly.
// ===========================================================================
__global__ __launch_bounds__(BLK_F, 4)
void fused3_k(const float* __restrict__ fp, const int* __restrict__ adj,
              const int* __restrict__ in_idx, const float* __restrict__ dem,
              const int* __restrict__ nn, float* __restrict__ wout,
              float* __restrict__ Ra, float* __restrict__ Rb,
              unsigned* __restrict__ bar_cnt, unsigned* __restrict__ bar_gen,
              int nodes) {
    const int N = *nn;
    const unsigned nb = gridDim.x;
    unsigned bar = 0;

    // ---- block -> node range ----
    int start, end;
    if (nodes == 4 * N && nb == GRID_F) {
        // XCD affinity: blocks dispatch round-robin over 8 XCDs (blockIdx%8).
        // Give XCD pair {2B, 2B+1} batch B so each XCD gathers only from its
        // own batch's R segment. Perf heuristic only — correct regardless.
        int batch = (blockIdx.x & 7) >> 1;                 // 0..3
        int rank  = ((blockIdx.x >> 3) << 1) | (blockIdx.x & 1);  // 0..63
        int per   = (N + 63) >> 6;
        int bend  = batch * N + N;
        start = batch * N + rank * per;
        end   = start + per;
        if (end > bend) end = bend;
        if (start > bend) start = bend;
    } else {
        int per = (nodes + nb - 1) / nb;
        start = blockIdx.x * per;
        end   = start + per;
        if (end > nodes) end = nodes;
        if (start > nodes) start = nodes;
    }

    const int n0 = start + (int)threadIdx.x;
    const int n1 = start + (int)threadIdx.x + BLK_F;
    const bool a0 = (n0 < end);
    const bool a1 = (n1 < end);
    const size_t b0 = (size_t)n0 * DEG, b1 = (size_t)n1 * DEG;

    // ---- phase 0: softmax ----
    if (a0) softmax_row(fp, adj, wout, b0, N);
    if (a1) softmax_row(fp, adj, wout, b1, N);
    grid_barrier(bar_cnt, bar_gen, ++bar, nb);

    // ---- phase 1: register-resident edge tables ----
    int   src0[DEG], src1[DEG];
    float w0[DEG],   w1[DEG];
    float d0 = 0.f, d1 = 0.f;
#pragma unroll
    for (int k = 0; k < DEG; ++k) { src0[k] = 0; w0[k] = 0.f; src1[k] = 0; w1[k] = 0.f; }
    if (a0) { d0 = dem[n0]; load_edges(in_idx, wout, n0, N, src0, w0); }
    if (a1) { d1 = dem[n1]; load_edges(in_idx, wout, n1, N, src1, w1); }

    // wave-uniform skip masks (bit k set => every lane's slot-k weight is 0)
    unsigned skipA = 0, skipB = 0;
#pragma unroll
    for (int k = 0; k < DEG; ++k) {
        if (__ballot(w0[k] != 0.f) == 0ull) skipA |= (1u << k);
        if (__ballot(w1[k] != 0.f) == 0ull) skipB |= (1u << k);
    }
    const unsigned sk0 = __builtin_amdgcn_readfirstlane(skipA);
    const unsigned sk1 = __builtin_amdgcn_readfirstlane(skipB);

    // ---- phase 2: iteration 1 analytically (R_0 == 0) ----
    float r0 = fmaxf(-d0, 0.f), r1 = fmaxf(-d1, 0.f);
    if (a0) Ra[n0] = r0;
    if (a1) Ra[n1] = r1;
    grid_barrier(bar_cnt, bar_gen, ++bar, nb);

    // ---- phase 3: iterations 2..32 (last one not published) ----
    const float* Rin = Ra;
    float*       Rout = Rb;
    for (int t = 1; t < MAX_ITERS; ++t) {
        float acc0 = 0.f, acc1 = 0.f;
        if (a0) {
#pragma unroll
            for (int k = 0; k < DEG; ++k)
                if (!((sk0 >> k) & 1u)) acc0 += w0[k] * Rin[src0[k]];
        }
        if (a1) {
#pragma unroll
            for (int k = 0; k < DEG; ++k)
                if (!((sk1 >> k) & 1u)) acc1 += w1[k] * Rin[src1[k]];
        }
        r0 = fmaxf(acc0 - d0, 0.f);
        r1 = fmaxf(acc1 - d1, 0.f);
        if (t < MAX_ITERS - 1) {
            if (a0) Rout[n0] = r0;
            if (a1) Rout[n1] = r1;
            grid_barrier(bar_cnt, bar_gen, ++bar, nb);
            float* tmp = (float*)Rin; Rin = Rout; Rout = tmp;
        }
    }

    // ---- phase 4: epilogue ----
    if (a0) {
        float4* w4 = (float4*)(wout + b0);
#pragma unroll
        for (int k = 0; k < DEG / 4; ++k) {
            float4 v = w4[k];
            v.x *= r0; v.y *= r0; v.z *= r0; v.w *= r0;
            w4[k] = v;
        }
    }
    if (a1) {
        float4* w4 = (float4*)(wout + b1);
#pragma unroll
        for (int k = 0; k < DEG / 4; ++k) {
            float4 v = w4[k];
            v.x *= r1; v.y *= r1; v.z *= r1; v.w *= r1;
            w4[k] = v;
        }
    }
}

// ===========================================================================
// FALLBACK PATH (round-1 kernels, known-correct 1028 us)
// ===========================================================================
__global__ void softmax_k(const float* __restrict__ fp, const int* __restrict__ adj,
                          const int* __restrict__ nn, float* __restrict__ wout,
                          int nodes) {
    int i = blockIdx.x * blockDim.x + threadIdx.x;
    if (i >= nodes) return;
    softmax_row(fp, adj, wout, (size_t)i * DEG, *nn);
}

__global__ void gather_k(const int* __restrict__ in_idx, const float* __restrict__ w,
                         const int* __restrict__ nn, int* __restrict__ e_src,
                         float* __restrict__ e_w, int edges) {
    int e = blockIdx.x * blockDim.x + threadIdx.x;
    if (e >= edges) return;
    const int N = *nn;
    size_t e3 = 3 * (size_t)e;
    int fi = in_idx[e3] * N + in_idx[e3 + 1];
    e_src[e] = fi;
    e_w[e]   = w[(size_t)fi * DEG + in_idx[e3 + 2]];
}

__global__ void iter_k(const int* __restrict__ e_src, const float* __restrict__ e_w,
                       const float* __restrict__ dem, const float* __restrict__ Rin,
                       float* __restrict__ Rout, int nodes) {
    int i = blockIdx.x * blockDim.x + threadIdx.x;
    if (i >= nodes) return;
    const size_t base = (size_t)i * DEG;
    const int4*   s4 = (const int4*)(e_src + base);
    const float4* w4 = (const float4*)(e_w + base);
    float acc = 0.f;
#pragma unroll
    for (int k = 0; k < DEG / 4; ++k) {
        int4   s = s4[k];
        float4 w = w4[k];
        acc += w.x * Rin[s.x];
        acc += w.y * Rin[s.y];
        acc += w.z * Rin[s.z];
        acc += w.w * Rin[s.w];
    }
    float r = acc - dem[i];
    Rout[i] = r > 0.f ? r : 0.f;
}

__global__ void final_k(const float* __restrict__ w, const float* __restrict__ R,
                        float* __restrict__ out, int nodes) {
    int i = blockIdx.x * blockDim.x + threadIdx.x;
    if (i >= nodes) return;
    float r = R[i];
    const size_t base = (size_t)i * DEG;
    const float4* w4 = (const float4*)(w + base);
    float4* o4 = (float4*)(out + base);
#pragma unroll
    for (int k = 0; k < DEG / 4; ++k) {
        float4 v = w4[k];
        v.x *= r; v.y *= r; v.z *= r; v.w *= r;
        o4[k] = v;
    }
}

extern "C" void kernel_launch(void* const* d_in, const int* in_sizes, int n_in,
                              void* d_out, int out_size, void* d_ws, size_t ws_size,
                              hipStream_t stream) {
    const float* fp  = (const float*)d_in[0];
    const float* dem = (const float*)d_in[1];
    const int*   adj = (const int*)d_in[2];
    const int*   idx = (const int*)d_in[3];
    const int*   nn  = (const int*)d_in[4];

    const int edges = in_sizes[0];   // B*N*D
    const int nodes = in_sizes[1];   // B*N

    float* weights = (float*)d_out;

    char* ws = (char*)d_ws;
    // barrier words at head of ws (overlaps e_src, which only the mutually-
    // exclusive fallback path uses)
    unsigned* bar_cnt = (unsigned*)ws;
    unsigned* bar_gen = (unsigned*)(ws + 128);
    int*   e_src = (int*)ws;
    float* e_w   = (float*)(ws + (size_t)edges * sizeof(int));
    float* R0    = (float*)(ws + (size_t)edges * sizeof(int) + (size_t)edges * sizeof(float));
    float* R1    = R0 + nodes;

    int dev = 0, cus = 0, maxBlk = 0;
    hipGetDevice(&dev);
    hipDeviceGetAttribute(&cus, hipDeviceAttributeMultiprocessorCount, dev);
    hipOccupancyMaxActiveBlocksPerMultiprocessor(&maxBlk, (const void*)fused3_k,
                                                 BLK_F, 0);

    const int per_blk = (nodes + GRID_F - 1) / GRID_F;   // nodes per block

    if (maxBlk >= 1 && cus >= GRID_F && per_blk <= 2 * BLK_F) {
        hipMemsetAsync(ws, 0, 256, stream);   // zero barrier words
        void* args[] = { (void*)&fp, (void*)&adj, (void*)&idx, (void*)&dem,
                         (void*)&nn, (void*)&weights, (void*)&R0, (void*)&R1,
                         (void*)&bar_cnt, (void*)&bar_gen, (void*)&nodes };
        hipLaunchCooperativeKernel((const void*)fused3_k, dim3(GRID_F), dim3(BLK_F),
                                   args, 0, stream);
    } else {
        const int blk = 256;
        const int gn = (nodes + blk - 1) / blk;
        const int ge = (edges + blk - 1) / blk;
        hipMemsetAsync(R0, 0, (size_t)nodes * sizeof(float), stream);
        softmax_k<<<gn, blk, 0, stream>>>(fp, adj, nn, weights, nodes);
        gather_k<<<ge, blk, 0, stream>>>(idx, weights, nn, e_src, e_w, edges);
        float* a = R0;
        float* b = R1;
        for (int t = 0; t < MAX_ITERS; ++t) {
            iter_k<<<gn, blk, 0, stream>>>(e_src, e_w, dem, a, b, nodes);
            float* tmp = a; a = b; b = tmp;
        }
        final_k<<<gn, blk, 0, stream>>>(weights, a, (float*)d_out, nodes);
    }
}

// Round 5
// 1026.470 us; speedup vs baseline: 1.0022x; 1.0022x over previous
//
#include <hip/hip_runtime.h>

#define DEG 16
#define MAX_ITERS 32
#define BLK_F 1024
#define GRID_F 256
#define CHUNK_LOG 14
#define CHUNK (1 << CHUNK_LOG)      // 16384 floats = 64 KB LDS chunk
#define SENTINEL 0x7FFFFFFF

// ===========================================================================
// Grid barrier (R3/R4-proven): one atomic arrival per block, monotone gen
// counter, agent-scope. Requires *cnt == *gen == 0 at kernel start.
// ===========================================================================
__device__ __forceinline__ void grid_barrier(unsigned* cnt, unsigned* gen,
                                             unsigned target, unsigned nblocks) {
    __syncthreads();
    if (threadIdx.x == 0) {
        __threadfence();                  // release
        unsigned arrived = __hip_atomic_fetch_add(cnt, 1u, __ATOMIC_ACQ_REL,
                                                  __HIP_MEMORY_SCOPE_AGENT);
        if (arrived == nblocks - 1u) {
            __hip_atomic_store(cnt, 0u, __ATOMIC_RELAXED, __HIP_MEMORY_SCOPE_AGENT);
            __hip_atomic_fetch_add(gen, 1u, __ATOMIC_RELEASE, __HIP_MEMORY_SCOPE_AGENT);
        } else {
            while (__hip_atomic_load(gen, __ATOMIC_RELAXED,
                                     __HIP_MEMORY_SCOPE_AGENT) < target) {
                __builtin_amdgcn_s_sleep(2);
            }
        }
        __threadfence();                  // acquire
    }
    __syncthreads();
}

__device__ __forceinline__ void softmax_row(const float* __restrict__ fp,
                                            const int* __restrict__ adj,
                                            float* __restrict__ wout,
                                            size_t base, int N) {
    const float4* f4 = (const float4*)(fp + base);
    const int4*   a4 = (const int4*)(adj + base);
    float v[DEG];
#pragma unroll
    for (int k = 0; k < DEG / 4; ++k) {
        float4 f = f4[k];
        int4   a = a4[k];
        v[4*k+0] = (a.x == N) ? f.x - 1e7f : f.x;
        v[4*k+1] = (a.y == N) ? f.y - 1e7f : f.y;
        v[4*k+2] = (a.z == N) ? f.z - 1e7f : f.z;
        v[4*k+3] = (a.w == N) ? f.w - 1e7f : f.w;
    }
    float m = v[0];
#pragma unroll
    for (int j = 1; j < DEG; ++j) m = fmaxf(m, v[j]);
    float s = 0.f;
#pragma unroll
    for (int j = 0; j < DEG; ++j) { v[j] = __expf(v[j] - m); s += v[j]; }
    float inv = 1.f / s;
    float4* w4 = (float4*)(wout + base);
#pragma unroll
    for (int k = 0; k < DEG / 4; ++k) {
        float4 o;
        o.x = v[4*k+0] * inv;
        o.y = v[4*k+1] * inv;
        o.z = v[4*k+2] * inv;
        o.w = v[4*k+3] * inv;
        w4[k] = o;
    }
}

__device__ __forceinline__ void load_edges(const int* __restrict__ in_idx,
                                           const float* __restrict__ wsrc,
                                           int n, int N,
                                           int* __restrict__ src,
                                           float* __restrict__ w) {
    const int4* t4 = (const int4*)(in_idx + 3 * (size_t)n * DEG);
#pragma unroll
    for (int g = 0; g < 4; ++g) {
        int4 qa = t4[3*g + 0];
        int4 qb = t4[3*g + 1];
        int4 qc = t4[3*g + 2];
        int f0 = qa.x * N + qa.y;  int l0 = qa.z;
        int f1 = qa.w * N + qb.x;  int l1 = qb.y;
        int f2 = qb.z * N + qb.w;  int l2 = qc.x;
        int f3 = qc.y * N + qc.z;  int l3 = qc.w;
        src[4*g+0] = f0; src[4*g+1] = f1; src[4*g+2] = f2; src[4*g+3] = f3;
        w[4*g+0] = wsrc[(size_t)f0 * DEG + l0];   // padded -> exactly 0.0f
        w[4*g+1] = wsrc[(size_t)f1 * DEG + l1];
        w[4*g+2] = wsrc[(size_t)f2 * DEG + l2];
        w[4*g+3] = wsrc[(size_t)f3 * DEG + l3];
    }
}

// bitonic sort of 16 (src,w) pairs by src — constant indices, stays in VGPRs
__device__ __forceinline__ void sort16(int* __restrict__ s, float* __restrict__ w) {
#pragma unroll
    for (int k = 2; k <= 16; k <<= 1) {
#pragma unroll
        for (int j = k >> 1; j > 0; j >>= 1) {
#pragma unroll
            for (int i = 0; i < 16; ++i) {
                int ixj = i ^ j;
                if (ixj > i) {
                    const bool up = ((i & k) == 0);
                    int sa = s[i], sb = s[ixj];
                    bool sw = up ? (sa > sb) : (sa < sb);
                    if (sw) {
                        s[i] = sb; s[ixj] = sa;
                        float t = w[i]; w[i] = w[ixj]; w[ixj] = t;
                    }
                }
            }
        }
    }
}

// ===========================================================================
// FUSED PATH v5: LDS-staged gather. Per round, each block sweeps the R
// segment its edges touch in 64 KB chunks: coalesced global->LDS staging,
// then register-held edges consume from LDS (ds_read, ~6cyc) instead of
// issuing 4B random GLOBAL requests (the R1-R4 invariant bottleneck).
// Edges sorted by src; padded slots sentinelized (never staged/issued).
// ===========================================================================
__global__ __launch_bounds__(BLK_F, 4)
void fused5_k(const float* __restrict__ fp, const int* __restrict__ adj,
              const int* __restrict__ in_idx, const float* __restrict__ dem,
              const int* __restrict__ nn, float* __restrict__ wout,
              float* __restrict__ Ra, float* __restrict__ Rb,
              unsigned* __restrict__ bar_cnt, unsigned* __restrict__ bar_gen,
              int nodes) {
    __shared__ float lds[CHUNK];
    __shared__ int s_mn, s_mx;

    const int N = *nn;
    const unsigned nb = gridDim.x;
    unsigned bar = 0;

    // ---- block -> node range (XCD-batch affinity heuristic; correct for any
    //      mapping since staging range is derived from actual edge srcs) ----
    int start, end;
    if (nodes == 4 * N && nb == GRID_F) {
        int batch = (blockIdx.x & 7) >> 1;
        int rank  = ((blockIdx.x >> 3) << 1) | (blockIdx.x & 1);
        int per   = (N + 63) >> 6;
        int bend  = batch * N + N;
        start = batch * N + rank * per;
        end   = start + per;
        if (end > bend) end = bend;
        if (start > bend) start = bend;
    } else {
        int per = (nodes + nb - 1) / nb;
        start = blockIdx.x * per;
        end   = start + per;
        if (end > nodes) end = nodes;
        if (start > nodes) start = nodes;
    }

    const int n0 = start + (int)threadIdx.x;
    const int n1 = start + (int)threadIdx.x + BLK_F;
    const bool a0 = (n0 < end), a1 = (n1 < end);
    const size_t b0 = (size_t)n0 * DEG, b1 = (size_t)n1 * DEG;

    // ---- phase 0: softmax ----
    if (a0) softmax_row(fp, adj, wout, b0, N);
    if (a1) softmax_row(fp, adj, wout, b1, N);
    grid_barrier(bar_cnt, bar_gen, ++bar, nb);

    // ---- phase 1: edge tables -> registers; sentinelize zero-weight slots ----
    int   src0[DEG], src1[DEG];
    float w0[DEG],   w1[DEG];
    float d0 = 0.f, d1 = 0.f;
#pragma unroll
    for (int k = 0; k < DEG; ++k) { src0[k] = SENTINEL; w0[k] = 0.f;
                                    src1[k] = SENTINEL; w1[k] = 0.f; }
    if (a0) { d0 = dem[n0]; load_edges(in_idx, wout, n0, N, src0, w0); }
    if (a1) { d1 = dem[n1]; load_edges(in_idx, wout, n1, N, src1, w1); }
#pragma unroll
    for (int k = 0; k < DEG; ++k) {
        if (w0[k] == 0.f) src0[k] = SENTINEL;   // contributes 0 either way
        if (w1[k] == 0.f) src1[k] = SENTINEL;
    }
    sort16(src0, w0);
    sort16(src1, w1);

    // ---- block-uniform chunk range from actual srcs ----
    int mn = SENTINEL, mx = -1;
#pragma unroll
    for (int k = 0; k < DEG; ++k) {
        if (src0[k] != SENTINEL) { mn = min(mn, src0[k]); mx = max(mx, src0[k]); }
        if (src1[k] != SENTINEL) { mn = min(mn, src1[k]); mx = max(mx, src1[k]); }
    }
    if (threadIdx.x == 0) { s_mn = SENTINEL; s_mx = -1; }
    __syncthreads();
    atomicMin(&s_mn, mn);
    atomicMax(&s_mx, mx);
    __syncthreads();
    const int c_lo = (s_mn == SENTINEL) ? 1 : (s_mn >> CHUNK_LOG);
    const int c_hi = (s_mx < 0) ? 0 : (s_mx >> CHUNK_LOG);

    // ---- phase 2: iteration 1 analytically (R_0 == 0) ----
    float r0 = fmaxf(-d0, 0.f), r1 = fmaxf(-d1, 0.f);
    if (a0) Ra[n0] = r0;
    if (a1) Ra[n1] = r1;
    grid_barrier(bar_cnt, bar_gen, ++bar, nb);

    // ---- phase 3: iterations 2..32 via LDS-chunk sweep ----
    const float* Rin = Ra;
    float*       Rout = Rb;
    for (int t = 1; t < MAX_ITERS; ++t) {
        float acc0 = 0.f, acc1 = 0.f;
        for (int c = c_lo; c <= c_hi; ++c) {
            const int cbase = c << CHUNK_LOG;
            // coalesced stage: 16 floats/thread (4x float4)
#pragma unroll
            for (int q = 0; q < CHUNK / (BLK_F * 4); ++q) {
                int li = (q * BLK_F + (int)threadIdx.x) * 4;
                int gi = cbase + li;
                if (gi + 4 <= nodes) {
                    float4 v = *(const float4*)(Rin + gi);
                    *(float4*)(lds + li) = v;
                } else {
#pragma unroll
                    for (int e = 0; e < 4; ++e)
                        lds[li + e] = (gi + e < nodes) ? Rin[gi + e] : 0.f;
                }
            }
            __syncthreads();
#pragma unroll
            for (int k = 0; k < DEG; ++k) {
                if ((unsigned)(src0[k] - cbase) < (unsigned)CHUNK)
                    acc0 += w0[k] * lds[src0[k] - cbase];
                if ((unsigned)(src1[k] - cbase) < (unsigned)CHUNK)
                    acc1 += w1[k] * lds[src1[k] - cbase];
            }
            __syncthreads();
        }
        r0 = fmaxf(acc0 - d0, 0.f);
        r1 = fmaxf(acc1 - d1, 0.f);
        if (t < MAX_ITERS - 1) {
            if (a0) Rout[n0] = r0;
            if (a1) Rout[n1] = r1;
            grid_barrier(bar_cnt, bar_gen, ++bar, nb);
            float* tmp = (float*)Rin; Rin = Rout; Rout = tmp;
        }
    }

    // ---- phase 4: epilogue ----
    if (a0) {
        float4* w4 = (float4*)(wout + b0);
#pragma unroll
        for (int k = 0; k < DEG / 4; ++k) {
            float4 v = w4[k];
            v.x *= r0; v.y *= r0; v.z *= r0; v.w *= r0;
            w4[k] = v;
        }
    }
    if (a1) {
        float4* w4 = (float4*)(wout + b1);
#pragma unroll
        for (int k = 0; k < DEG / 4; ++k) {
            float4 v = w4[k];
            v.x *= r1; v.y *= r1; v.z *= r1; v.w *= r1;
            w4[k] = v;
        }
    }
}

// ===========================================================================
// FALLBACK PATH (round-1 kernels, known-correct 1028 us)
// ===========================================================================
__global__ void softmax_k(const float* __restrict__ fp, const int* __restrict__ adj,
                          const int* __restrict__ nn, float* __restrict__ wout,
                          int nodes) {
    int i = blockIdx.x * blockDim.x + threadIdx.x;
    if (i >= nodes) return;
    softmax_row(fp, adj, wout, (size_t)i * DEG, *nn);
}

__global__ void gather_k(const int* __restrict__ in_idx, const float* __restrict__ w,
                         const int* __restrict__ nn, int* __restrict__ e_src,
                         float* __restrict__ e_w, int edges) {
    int e = blockIdx.x * blockDim.x + threadIdx.x;
    if (e >= edges) return;
    const int N = *nn;
    size_t e3 = 3 * (size_t)e;
    int fi = in_idx[e3] * N + in_idx[e3 + 1];
    e_src[e] = fi;
    e_w[e]   = w[(size_t)fi * DEG + in_idx[e3 + 2]];
}

__global__ void iter_k(const int* __restrict__ e_src, const float* __restrict__ e_w,
                       const float* __restrict__ dem, const float* __restrict__ Rin,
                       float* __restrict__ Rout, int nodes) {
    int i = blockIdx.x * blockDim.x + threadIdx.x;
    if (i >= nodes) return;
    const size_t base = (size_t)i * DEG;
    const int4*   s4 = (const int4*)(e_src + base);
    const float4* w4 = (const float4*)(e_w + base);
    float acc = 0.f;
#pragma unroll
    for (int k = 0; k < DEG / 4; ++k) {
        int4   s = s4[k];
        float4 w = w4[k];
        acc += w.x * Rin[s.x];
        acc += w.y * Rin[s.y];
        acc += w.z * Rin[s.z];
        acc += w.w * Rin[s.w];
    }
    float r = acc - dem[i];
    Rout[i] = r > 0.f ? r : 0.f;
}

__global__ void final_k(const float* __restrict__ w, const float* __restrict__ R,
                        float* __restrict__ out, int nodes) {
    int i = blockIdx.x * blockDim.x + threadIdx.x;
    if (i >= nodes) return;
    float r = R[i];
    const size_t base = (size_t)i * DEG;
    const float4* w4 = (const float4*)(w + base);
    float4* o4 = (float4*)(out + base);
#pragma unroll
    for (int k = 0; k < DEG / 4; ++k) {
        float4 v = w4[k];
        v.x *= r; v.y *= r; v.z *= r; v.w *= r;
        o4[k] = v;
    }
}

extern "C" void kernel_launch(void* const* d_in, const int* in_sizes, int n_in,
                              void* d_out, int out_size, void* d_ws, size_t ws_size,
                              hipStream_t stream) {
    const float* fp  = (const float*)d_in[0];
    const float* dem = (const float*)d_in[1];
    const int*   adj = (const int*)d_in[2];
    const int*   idx = (const int*)d_in[3];
    const int*   nn  = (const int*)d_in[4];

    const int edges = in_sizes[0];   // B*N*D
    const int nodes = in_sizes[1];   // B*N

    float* weights = (float*)d_out;

    char* ws = (char*)d_ws;
    // fused-path layout: barrier words + R ping-pong
    unsigned* bar_cnt = (unsigned*)ws;
    unsigned* bar_gen = (unsigned*)(ws + 128);
    float* R0f = (float*)(ws + 256);
    float* R1f = R0f + nodes;
    // fallback layout (mutually exclusive with fused path)
    int*   e_src = (int*)ws;
    float* e_w   = (float*)(ws + (size_t)edges * sizeof(int));
    float* R0    = (float*)(ws + (size_t)edges * sizeof(int) + (size_t)edges * sizeof(float));
    float* R1    = R0 + nodes;

    int dev = 0, cus = 0, maxBlk = 0;
    hipGetDevice(&dev);
    hipDeviceGetAttribute(&cus, hipDeviceAttributeMultiprocessorCount, dev);
    hipOccupancyMaxActiveBlocksPerMultiprocessor(&maxBlk, (const void*)fused5_k,
                                                 BLK_F, 0);

    const int per_blk = (nodes + GRID_F - 1) / GRID_F;

    if (maxBlk >= 1 && cus >= GRID_F && per_blk <= 2 * BLK_F) {
        hipMemsetAsync(ws, 0, 256, stream);   // zero barrier words
        void* args[] = { (void*)&fp, (void*)&adj, (void*)&idx, (void*)&dem,
                         (void*)&nn, (void*)&weights, (void*)&R0f, (void*)&R1f,
                         (void*)&bar_cnt, (void*)&bar_gen, (void*)&nodes };
        hipLaunchCooperativeKernel((const void*)fused5_k, dim3(GRID_F), dim3(BLK_F),
                                   args, 0, stream);
    } else {
        const int blk = 256;
        const int gn = (nodes + blk - 1) / blk;
        const int ge = (edges + blk - 1) / blk;
        hipMemsetAsync(R0, 0, (size_t)nodes * sizeof(float), stream);
        softmax_k<<<gn, blk, 0, stream>>>(fp, adj, nn, weights, nodes);
        gather_k<<<ge, blk, 0, stream>>>(idx, weights, nn, e_src, e_w, edges);
        float* a = R0;
        float* b = R1;
        for (int t = 0; t < MAX_ITERS; ++t) {
            iter_k<<<gn, blk, 0, stream>>>(e_src, e_w, dem, a, b, nodes);
            float* tmp = a; a = b; b = tmp;
        }
        final_k<<<gn, blk, 0, stream>>>(weights, a, (float*)d_out, nodes);
    }
}

// Round 6
// 1024.838 us; speedup vs baseline: 1.0038x; 1.0016x over previous
//
#include <hip/hip_runtime.h>

#define DEG 16
#define E12 12
#define MAX_ITERS 32
#define BLK 1024

// ---------------------------------------------------------------------------
// sc0 data ops: agent-scope relaxed atomics -> L1-bypassing L2 accesses with
// NO fence/cache-maintenance codegen. Within one XCD's L2 these are
// physically coherent between blocks.
// ---------------------------------------------------------------------------
__device__ __forceinline__ float ld_sc0(const float* p) {
    return __hip_atomic_load(p, __ATOMIC_RELAXED, __HIP_MEMORY_SCOPE_AGENT);
}
__device__ __forceinline__ void st_sc0(float* p, float v) {
    __hip_atomic_store(p, v, __ATOMIC_RELAXED, __HIP_MEMORY_SCOPE_AGENT);
}
__device__ __forceinline__ unsigned ld_u32_sc0(const unsigned* p) {
    return __hip_atomic_load(p, __ATOMIC_RELAXED, __HIP_MEMORY_SCOPE_AGENT);
}

__device__ __forceinline__ int get_xcd() {
    unsigned x;
    asm volatile("s_getreg_b32 %0, hwreg(HW_REG_XCC_ID)" : "=s"(x));
    return (int)(x & 7u);
}

// ---------------------------------------------------------------------------
// GLOBAL barrier (R3-proven): agent-scope, with __threadfence (L2 wb/inv) —
// used only in the prologue and in the slow path.
// ---------------------------------------------------------------------------
__device__ __forceinline__ void grid_barrier(unsigned* cnt, unsigned* gen,
                                             unsigned target, unsigned nblocks) {
    __syncthreads();
    if (threadIdx.x == 0) {
        __threadfence();
        unsigned arrived = __hip_atomic_fetch_add(cnt, 1u, __ATOMIC_ACQ_REL,
                                                  __HIP_MEMORY_SCOPE_AGENT);
        if (arrived == nblocks - 1u) {
            __hip_atomic_store(cnt, 0u, __ATOMIC_RELAXED, __HIP_MEMORY_SCOPE_AGENT);
            __hip_atomic_fetch_add(gen, 1u, __ATOMIC_RELEASE, __HIP_MEMORY_SCOPE_AGENT);
        } else {
            while (__hip_atomic_load(gen, __ATOMIC_RELAXED,
                                     __HIP_MEMORY_SCOPE_AGENT) < target)
                __builtin_amdgcn_s_sleep(2);
        }
        __threadfence();
    }
    __syncthreads();
}

// ---------------------------------------------------------------------------
// XCD-local barrier: workgroup-scope release RMW (s_waitcnt drain, atomic at
// local L2, NO buffer_wbl2 / buffer_inv). Poll is an sc0 load (fresh from
// local L2). All participants are blocks on the SAME XCD.
// ---------------------------------------------------------------------------
__device__ __forceinline__ void xcd_barrier(unsigned* cnt, unsigned* gen,
                                            unsigned target, unsigned nblocks) {
    __syncthreads();
    if (threadIdx.x == 0) {
        unsigned arrived = __hip_atomic_fetch_add(cnt, 1u, __ATOMIC_RELEASE,
                                                  __HIP_MEMORY_SCOPE_WORKGROUP);
        if (arrived == nblocks - 1u) {
            __hip_atomic_store(cnt, 0u, __ATOMIC_RELAXED,
                               __HIP_MEMORY_SCOPE_WORKGROUP);
            __hip_atomic_fetch_add(gen, 1u, __ATOMIC_RELEASE,
                                   __HIP_MEMORY_SCOPE_WORKGROUP);
        } else {
            while (ld_u32_sc0(gen) < target)
                __builtin_amdgcn_s_sleep(2);
        }
    }
    __syncthreads();
}

__device__ __forceinline__ void softmax_row(const float* __restrict__ fp,
                                            const int* __restrict__ adj,
                                            float* __restrict__ wout,
                                            size_t base, int N) {
    const float4* f4 = (const float4*)(fp + base);
    const int4*   a4 = (const int4*)(adj + base);
    float v[DEG];
#pragma unroll
    for (int k = 0; k < DEG / 4; ++k) {
        float4 f = f4[k];
        int4   a = a4[k];
        v[4*k+0] = (a.x == N) ? f.x - 1e7f : f.x;
        v[4*k+1] = (a.y == N) ? f.y - 1e7f : f.y;
        v[4*k+2] = (a.z == N) ? f.z - 1e7f : f.z;
        v[4*k+3] = (a.w == N) ? f.w - 1e7f : f.w;
    }
    float m = v[0];
#pragma unroll
    for (int j = 1; j < DEG; ++j) m = fmaxf(m, v[j]);
    float s = 0.f;
#pragma unroll
    for (int j = 0; j < DEG; ++j) { v[j] = __expf(v[j] - m); s += v[j]; }
    float inv = 1.f / s;
    float4* w4 = (float4*)(wout + base);
#pragma unroll
    for (int k = 0; k < DEG / 4; ++k) {
        float4 o;
        o.x = v[4*k+0] * inv;
        o.y = v[4*k+1] * inv;
        o.z = v[4*k+2] * inv;
        o.w = v[4*k+3] * inv;
        w4[k] = o;
    }
}

// per-node accumulation, sc0 gathers from LOCAL (batch-relative) R slice
__device__ __forceinline__ float node_acc_sc0(const int* __restrict__ es,
                                              const float* __restrict__ ew,
                                              const float* __restrict__ Rc) {
    const int4*   s4 = (const int4*)es;
    const float4* w4 = (const float4*)ew;
    int4 a = s4[0], b = s4[1], c = s4[2];
    float4 x = w4[0], y = w4[1], z = w4[2];
    float acc;
    acc  = x.x * ld_sc0(Rc + a.x);
    acc += x.y * ld_sc0(Rc + a.y);
    acc += x.z * ld_sc0(Rc + a.z);
    acc += x.w * ld_sc0(Rc + a.w);
    acc += y.x * ld_sc0(Rc + b.x);
    acc += y.y * ld_sc0(Rc + b.y);
    acc += y.z * ld_sc0(Rc + b.z);
    acc += y.w * ld_sc0(Rc + b.w);
    acc += z.x * ld_sc0(Rc + c.x);
    acc += z.y * ld_sc0(Rc + c.y);
    acc += z.z * ld_sc0(Rc + c.z);
    acc += z.w * ld_sc0(Rc + c.w);
    return acc;
}

// plain-load variant for the slow (global-barrier) path
__device__ __forceinline__ float node_acc_plain(const int* __restrict__ es,
                                                const float* __restrict__ ew,
                                                const float* __restrict__ Rc) {
    const int4*   s4 = (const int4*)es;
    const float4* w4 = (const float4*)ew;
    int4 a = s4[0], b = s4[1], c = s4[2];
    float4 x = w4[0], y = w4[1], z = w4[2];
    float acc;
    acc  = x.x * Rc[a.x];
    acc += x.y * Rc[a.y];
    acc += x.z * Rc[a.z];
    acc += x.w * Rc[a.w];
    acc += y.x * Rc[b.x];
    acc += y.y * Rc[b.y];
    acc += y.z * Rc[b.z];
    acc += y.w * Rc[b.w];
    acc += z.x * Rc[c.x];
    acc += z.y * Rc[c.y];
    acc += z.z * Rc[c.z];
    acc += z.w * Rc[c.w];
    return acc;
}

// ===========================================================================
// FUSED v6: per-XCD redundant batch compute, XCD-local barriers, no
// device-scope fences in the round loop. On-device verified; multi-level
// fallbacks preserve correctness under any blockIdx->XCD mapping.
// ===========================================================================
__global__ __launch_bounds__(BLK, 8)   // 32 waves/CU -> 2 blocks/CU co-resident
void fused6_k(const float* __restrict__ fp, const int* __restrict__ adj,
              const int* __restrict__ in_idx, const float* __restrict__ dem,
              const int* __restrict__ nn, float* __restrict__ wout,
              char* __restrict__ wsb, int nodes) {
    unsigned* g_cnt   = (unsigned*)(wsb);
    unsigned* g_gen   = (unsigned*)(wsb + 128);
    unsigned* blkcnt  = (unsigned*)(wsb + 2304);   // [8]
    unsigned* ovf     = (unsigned*)(wsb + 2432);
    int*   e_src  = (int*)(wsb + 4096);
    float* e_w    = (float*)(wsb + 4096 + (size_t)E12 * nodes * 4);
    float* slices = e_w + (size_t)E12 * nodes;      // 8 xcd x 2 buf x Nb
    float* Rf     = slices + 4 * (size_t)nodes;     // slow-path ping-pong

    const int N  = *nn;
    const int Nb = N;                                // batch node count
    const unsigned nblocks = gridDim.x;
    const int tid = (int)threadIdx.x;

    __shared__ int sh_xcd, sh_rank, sh_mode, sh_K;
    unsigned gb = 0;

    // ---- phase S: self-organize (measure XCD, take rank) ----
    if (tid == 0) {
        int x = get_xcd();
        sh_xcd  = x;
        sh_rank = (int)__hip_atomic_fetch_add(&blkcnt[x], 1u, __ATOMIC_RELAXED,
                                              __HIP_MEMORY_SCOPE_AGENT);
    }
    __syncthreads();
    const int my_xcd  = sh_xcd;
    const int my_rank = sh_rank;

    // ---- phase 0: softmax (blockIdx partition, 1 node/thread) ----
    {
        int g = (int)blockIdx.x * BLK + tid;
        if (g < nodes) softmax_row(fp, adj, wout, (size_t)g * DEG, N);
    }
    grid_barrier(g_cnt, g_gen, ++gb, nblocks);

    // ---- decision input: per-XCD block counts ----
    if (tid == 0) {
        const int need = (Nb + 2 * BLK - 1) / (2 * BLK);
        unsigned c[8];
#pragma unroll
        for (int x = 0; x < 8; ++x) c[x] = ld_u32_sc0(&blkcnt[x]);
        bool ok = (4 * Nb == nodes) && (Nb > 0);
#pragma unroll
        for (int b = 0; b < 4; ++b)
            ok = ok && (c[2*b] >= (unsigned)need || c[2*b+1] >= (unsigned)need);
        sh_mode = ok ? 1 : 0;
        sh_K    = (int)c[my_xcd];
    }
    __syncthreads();

    // ---- phase 1: compact edge tables (blockIdx partition) ----
    {
        int g = (int)blockIdx.x * BLK + tid;
        if (g < nodes) {
            const int4* t4 = (const int4*)(in_idx + 3 * (size_t)g * DEG);
            int   cs[DEG]; float cw[DEG]; int cb[DEG];
#pragma unroll
            for (int q = 0; q < 4; ++q) {
                int4 qa = t4[3*q + 0];
                int4 qb = t4[3*q + 1];
                int4 qc = t4[3*q + 2];
                cb[4*q+0] = qa.x; cs[4*q+0] = qa.y; int l0 = qa.z;
                cb[4*q+1] = qa.w; cs[4*q+1] = qb.x; int l1 = qb.y;
                cb[4*q+2] = qb.z; cs[4*q+2] = qb.w; int l2 = qc.x;
                cb[4*q+3] = qc.y; cs[4*q+3] = qc.z; int l3 = qc.w;
                cw[4*q+0] = wout[((size_t)(cb[4*q+0]) * Nb + cs[4*q+0]) * DEG + l0];
                cw[4*q+1] = wout[((size_t)(cb[4*q+1]) * Nb + cs[4*q+1]) * DEG + l1];
                cw[4*q+2] = wout[((size_t)(cb[4*q+2]) * Nb + cs[4*q+2]) * DEG + l2];
                cw[4*q+3] = wout[((size_t)(cb[4*q+3]) * Nb + cs[4*q+3]) * DEG + l3];
            }
            // violations of the fast-mode assumptions -> flag
            const int gbatch = g / Nb;
            bool bad = (cw[12] != 0.f) || (cw[13] != 0.f) ||
                       (cw[14] != 0.f) || (cw[15] != 0.f);
#pragma unroll
            for (int k = 0; k < E12; ++k) bad = bad || (cb[k] != gbatch);
            if (bad)
                __hip_atomic_store(ovf, 1u, __ATOMIC_RELAXED,
                                   __HIP_MEMORY_SCOPE_AGENT);
            // store first 12 slots (zeros contribute nothing -> exact)
            int4*   es4 = (int4*)(e_src + (size_t)g * E12);
            float4* ew4 = (float4*)(e_w + (size_t)g * E12);
            es4[0] = make_int4(cs[0], cs[1], cs[2], cs[3]);
            es4[1] = make_int4(cs[4], cs[5], cs[6], cs[7]);
            es4[2] = make_int4(cs[8], cs[9], cs[10], cs[11]);
            ew4[0] = make_float4(cw[0], cw[1], cw[2], cw[3]);
            ew4[1] = make_float4(cw[4], cw[5], cw[6], cw[7]);
            ew4[2] = make_float4(cw[8], cw[9], cw[10], cw[11]);
        }
    }
    grid_barrier(g_cnt, g_gen, ++gb, nblocks);

    if (tid == 0) {
        if (ld_u32_sc0(ovf) != 0u) sh_mode = 0;
    }
    __syncthreads();
    const bool fast = (sh_mode == 1);

    if (fast) {
        // =================== FAST: XCD-local rounds ===================
        const int need = (Nb + 2 * BLK - 1) / (2 * BLK);
        const int K = sh_K;
        if (K < need) return;            // deficient XCD: partner covers batch

        const int batch = my_xcd >> 1;
        const int bbase = batch * Nb;
        const int base  = my_rank * (2 * BLK);
        const int l0 = base + tid;
        const int l1 = base + tid + BLK;
        const bool a0 = (l0 < Nb), a1 = (l1 < Nb);
        const int g0 = bbase + l0, g1 = bbase + l1;

        unsigned* xc = (unsigned*)(wsb + 256 + my_xcd * 256);
        unsigned* xg = (unsigned*)(wsb + 256 + my_xcd * 256 + 128);
        unsigned xb = 0;

        float* R0s = slices + (size_t)(my_xcd * 2 + 0) * Nb;
        float* R1s = slices + (size_t)(my_xcd * 2 + 1) * Nb;

        float d0 = a0 ? dem[g0] : 0.f;
        float d1 = a1 ? dem[g1] : 0.f;

        // iteration 1 analytic (R_0 == 0)
        float r0 = fmaxf(-d0, 0.f), r1 = fmaxf(-d1, 0.f);
        if (a0) st_sc0(R0s + l0, r0);
        if (a1) st_sc0(R1s + l1, r1);   // note: both buffers start identical
        if (a0) st_sc0(R1s + l0, r0);
        if (a1) st_sc0(R0s + l1, r1);
        xcd_barrier(xc, xg, ++xb, (unsigned)K);

        const float* Rc = R0s;
        float*       Rn = R1s;
        const int* es0 = e_src + (size_t)g0 * E12;
        const int* es1 = e_src + (size_t)g1 * E12;
        const float* ew0 = e_w + (size_t)g0 * E12;
        const float* ew1 = e_w + (size_t)g1 * E12;

        for (int t = 1; t < MAX_ITERS; ++t) {
            if (a0) r0 = fmaxf(node_acc_sc0(es0, ew0, Rc) - d0, 0.f);
            if (a1) r1 = fmaxf(node_acc_sc0(es1, ew1, Rc) - d1, 0.f);
            if (t < MAX_ITERS - 1) {
                if (a0) st_sc0(Rn + l0, r0);
                if (a1) st_sc0(Rn + l1, r1);
                xcd_barrier(xc, xg, ++xb, (unsigned)K);
                const float* tmp = Rc; Rc = Rn; Rn = (float*)tmp;
            }
        }

        // epilogue (pair-XCDs write identical values -> benign)
        if (a0) {
            float4* w4 = (float4*)(wout + (size_t)g0 * DEG);
#pragma unroll
            for (int k = 0; k < DEG / 4; ++k) {
                float4 v = w4[k];
                v.x *= r0; v.y *= r0; v.z *= r0; v.w *= r0;
                w4[k] = v;
            }
        }
        if (a1) {
            float4* w4 = (float4*)(wout + (size_t)g1 * DEG);
#pragma unroll
            for (int k = 0; k < DEG / 4; ++k) {
                float4 v = w4[k];
                v.x *= r1; v.y *= r1; v.z *= r1; v.w *= r1;
                w4[k] = v;
            }
        }
    } else {
        // =================== SLOW: global-barrier rounds (R4 semantics) =====
        const int g = (int)blockIdx.x * BLK + tid;
        const bool act = (g < nodes);
        int gbbase = 0;
        float d = 0.f;
        if (act) { gbbase = (g / Nb) * Nb; d = dem[g]; }
        const int*   es = e_src + (size_t)g * E12;
        const float* ew = e_w + (size_t)g * E12;

        float r = fmaxf(-d, 0.f);
        if (act) Rf[g] = r;
        grid_barrier(g_cnt, g_gen, ++gb, nblocks);

        const float* Rc = Rf;
        float*       Rn = Rf + nodes;
        for (int t = 1; t < MAX_ITERS; ++t) {
            if (act) r = fmaxf(node_acc_plain(es, ew, Rc + gbbase) - d, 0.f);
            if (t < MAX_ITERS - 1) {
                if (act) Rn[g] = r;
                grid_barrier(g_cnt, g_gen, ++gb, nblocks);
                const float* tmp = Rc; Rc = Rn; Rn = (float*)tmp;
            }
        }
        if (act) {
            float4* w4 = (float4*)(wout + (size_t)g * DEG);
#pragma unroll
            for (int k = 0; k < DEG / 4; ++k) {
                float4 v = w4[k];
                v.x *= r; v.y *= r; v.z *= r; v.w *= r;
                w4[k] = v;
            }
        }
    }
}

// ===========================================================================
// HOST FALLBACK (round-1 kernels, known-correct)
// ===========================================================================
__global__ void softmax_k(const float* __restrict__ fp, const int* __restrict__ adj,
                          const int* __restrict__ nn, float* __restrict__ wout,
                          int nodes) {
    int i = blockIdx.x * blockDim.x + threadIdx.x;
    if (i >= nodes) return;
    softmax_row(fp, adj, wout, (size_t)i * DEG, *nn);
}

__global__ void gather_k(const int* __restrict__ in_idx, const float* __restrict__ w,
                         const int* __restrict__ nn, int* __restrict__ e_srcO,
                         float* __restrict__ e_wO, int edges) {
    int e = blockIdx.x * blockDim.x + threadIdx.x;
    if (e >= edges) return;
    const int N = *nn;
    size_t e3 = 3 * (size_t)e;
    int fi = in_idx[e3] * N + in_idx[e3 + 1];
    e_srcO[e] = fi;
    e_wO[e]   = w[(size_t)fi * DEG + in_idx[e3 + 2]];
}

__global__ void iter_k(const int* __restrict__ e_srcO, const float* __restrict__ e_wO,
                       const float* __restrict__ dem, const float* __restrict__ Rin,
                       float* __restrict__ Rout, int nodes) {
    int i = blockIdx.x * blockDim.x + threadIdx.x;
    if (i >= nodes) return;
    const size_t base = (size_t)i * DEG;
    const int4*   s4 = (const int4*)(e_srcO + base);
    const float4* w4 = (const float4*)(e_wO + base);
    float acc = 0.f;
#pragma unroll
    for (int k = 0; k < DEG / 4; ++k) {
        int4   s = s4[k];
        float4 w = w4[k];
        acc += w.x * Rin[s.x];
        acc += w.y * Rin[s.y];
        acc += w.z * Rin[s.z];
        acc += w.w * Rin[s.w];
    }
    float r = acc - dem[i];
    Rout[i] = r > 0.f ? r : 0.f;
}

__global__ void final_k(const float* __restrict__ w, const float* __restrict__ R,
                        float* __restrict__ out, int nodes) {
    int i = blockIdx.x * blockDim.x + threadIdx.x;
    if (i >= nodes) return;
    float r = R[i];
    const size_t base = (size_t)i * DEG;
    const float4* w4 = (const float4*)(w + base);
    float4* o4 = (float4*)(out + base);
#pragma unroll
    for (int k = 0; k < DEG / 4; ++k) {
        float4 v = w4[k];
        v.x *= r; v.y *= r; v.z *= r; v.w *= r;
        o4[k] = v;
    }
}

extern "C" void kernel_launch(void* const* d_in, const int* in_sizes, int n_in,
                              void* d_out, int out_size, void* d_ws, size_t ws_size,
                              hipStream_t stream) {
    const float* fp  = (const float*)d_in[0];
    const float* dem = (const float*)d_in[1];
    const int*   adj = (const int*)d_in[2];
    const int*   idx = (const int*)d_in[3];
    const int*   nn  = (const int*)d_in[4];

    const int edges = in_sizes[0];   // B*N*D
    const int nodes = in_sizes[1];   // B*N

    float* weights = (float*)d_out;
    char*  ws      = (char*)d_ws;

    int dev = 0, cus = 0, maxBlk = 0;
    hipGetDevice(&dev);
    hipDeviceGetAttribute(&cus, hipDeviceAttributeMultiprocessorCount, dev);
    hipOccupancyMaxActiveBlocksPerMultiprocessor(&maxBlk, (const void*)fused6_k,
                                                 BLK, 0);

    const int grid = 2 * cus;
    const size_t ws_need = 4096 + (size_t)nodes * (E12 * 8 + 16 + 8);

    const bool fused_ok = (maxBlk >= 2) &&
                          ((long long)grid * BLK >= nodes) &&
                          (ws_size >= ws_need) &&
                          (nodes % 4 == 0);

    if (fused_ok) {
        hipMemsetAsync(ws, 0, 4096, stream);
        void* args[] = { (void*)&fp, (void*)&adj, (void*)&idx, (void*)&dem,
                         (void*)&nn, (void*)&weights, (void*)&ws, (void*)&nodes };
        hipLaunchCooperativeKernel((const void*)fused6_k, dim3(grid), dim3(BLK),
                                   args, 0, stream);
    } else {
        int*   e_srcO = (int*)ws;
        float* e_wO   = (float*)(ws + (size_t)edges * sizeof(int));
        float* R0     = (float*)(ws + (size_t)edges * 8);
        float* R1     = R0 + nodes;
        const int blk = 256;
        const int gn = (nodes + blk - 1) / blk;
        const int ge = (edges + blk - 1) / blk;
        hipMemsetAsync(R0, 0, (size_t)nodes * sizeof(float), stream);
        softmax_k<<<gn, blk, 0, stream>>>(fp, adj, nn, weights, nodes);
        gather_k<<<ge, blk, 0, stream>>>(idx, weights, nn, e_srcO, e_wO, edges);
        float* a = R0;
        float* b = R1;
        for (int t = 0; t < MAX_ITERS; ++t) {
            iter_k<<<gn, blk, 0, stream>>>(e_srcO, e_wO, dem, a, b, nodes);
            float* tmp = a; a = b; b = tmp;
        }
        final_k<<<gn, blk, 0, stream>>>(weights, a, (float*)d_out, nodes);
    }
}

// Round 7
// 1023.821 us; speedup vs baseline: 1.0048x; 1.0010x over previous
//
#include <hip/hip_runtime.h>

#define DEG 16
#define E12 12
#define MAX_ITERS 32
#define BLK 1024
#define LDSF 25600          // floats staged per chunk (100 KB LDS)
#define JMAX 96             // per-thread edge-stream budget (padded)

// ---------------------------------------------------------------------------
// sc0 ops: agent-scope relaxed -> L1-bypassing L2 access, no fence codegen.
// ---------------------------------------------------------------------------
__device__ __forceinline__ float ld_sc0(const float* p) {
    return __hip_atomic_load((float*)p, __ATOMIC_RELAXED, __HIP_MEMORY_SCOPE_AGENT);
}
__device__ __forceinline__ void st_sc0(float* p, float v) {
    __hip_atomic_store(p, v, __ATOMIC_RELAXED, __HIP_MEMORY_SCOPE_AGENT);
}
__device__ __forceinline__ unsigned ld_u32_sc0(const unsigned* p) {
    return __hip_atomic_load((unsigned*)p, __ATOMIC_RELAXED, __HIP_MEMORY_SCOPE_AGENT);
}
__device__ __forceinline__ void st_u32_sc0(unsigned* p, unsigned v) {
    __hip_atomic_store(p, v, __ATOMIC_RELAXED, __HIP_MEMORY_SCOPE_AGENT);
}

__device__ __forceinline__ int get_xcd() {
    unsigned x;
    asm volatile("s_getreg_b32 %0, hwreg(HW_REG_XCC_ID)" : "=s"(x));
    return (int)(x & 7u);
}

// global barrier (R3-proven; prologue / slow path only)
__device__ __forceinline__ void grid_barrier(unsigned* cnt, unsigned* gen,
                                             unsigned target, unsigned nblocks) {
    __syncthreads();
    if (threadIdx.x == 0) {
        __threadfence();
        unsigned arrived = __hip_atomic_fetch_add(cnt, 1u, __ATOMIC_ACQ_REL,
                                                  __HIP_MEMORY_SCOPE_AGENT);
        if (arrived == nblocks - 1u) {
            __hip_atomic_store(cnt, 0u, __ATOMIC_RELAXED, __HIP_MEMORY_SCOPE_AGENT);
            __hip_atomic_fetch_add(gen, 1u, __ATOMIC_RELEASE, __HIP_MEMORY_SCOPE_AGENT);
        } else {
            while (__hip_atomic_load(gen, __ATOMIC_RELAXED,
                                     __HIP_MEMORY_SCOPE_AGENT) < target)
                __builtin_amdgcn_s_sleep(2);
        }
        __threadfence();
    }
    __syncthreads();
}

// XCD-local barrier (R6-proven; no cache maintenance)
__device__ __forceinline__ void xcd_barrier(unsigned* cnt, unsigned* gen,
                                            unsigned target, unsigned nblocks) {
    __syncthreads();
    if (threadIdx.x == 0) {
        unsigned arrived = __hip_atomic_fetch_add(cnt, 1u, __ATOMIC_RELEASE,
                                                  __HIP_MEMORY_SCOPE_WORKGROUP);
        if (arrived == nblocks - 1u) {
            __hip_atomic_store(cnt, 0u, __ATOMIC_RELAXED,
                               __HIP_MEMORY_SCOPE_WORKGROUP);
            __hip_atomic_fetch_add(gen, 1u, __ATOMIC_RELEASE,
                                   __HIP_MEMORY_SCOPE_WORKGROUP);
        } else {
            while (ld_u32_sc0(gen) < target)
                __builtin_amdgcn_s_sleep(2);
        }
    }
    __syncthreads();
}

__device__ __forceinline__ void softmax_row(const float* __restrict__ fp,
                                            const int* __restrict__ adj,
                                            float* __restrict__ wout,
                                            size_t base, int N) {
    const float4* f4 = (const float4*)(fp + base);
    const int4*   a4 = (const int4*)(adj + base);
    float v[DEG];
#pragma unroll
    for (int k = 0; k < DEG / 4; ++k) {
        float4 f = f4[k];
        int4   a = a4[k];
        v[4*k+0] = (a.x == N) ? f.x - 1e7f : f.x;
        v[4*k+1] = (a.y == N) ? f.y - 1e7f : f.y;
        v[4*k+2] = (a.z == N) ? f.z - 1e7f : f.z;
        v[4*k+3] = (a.w == N) ? f.w - 1e7f : f.w;
    }
    float m = v[0];
#pragma unroll
    for (int j = 1; j < DEG; ++j) m = fmaxf(m, v[j]);
    float s = 0.f;
#pragma unroll
    for (int j = 0; j < DEG; ++j) { v[j] = __expf(v[j] - m); s += v[j]; }
    float inv = 1.f / s;
    float4* w4 = (float4*)(wout + base);
#pragma unroll
    for (int k = 0; k < DEG / 4; ++k) {
        float4 o;
        o.x = v[4*k+0] * inv;
        o.y = v[4*k+1] * inv;
        o.z = v[4*k+2] * inv;
        o.w = v[4*k+3] * inv;
        w4[k] = o;
    }
}

// E12 accumulate: 12 gathers from Rc (batch-local indices)
__device__ __forceinline__ float node_acc12(const int* __restrict__ es,
                                            const float* __restrict__ ew,
                                            const float* __restrict__ Rc) {
    const int4*   s4 = (const int4*)es;
    const float4* w4 = (const float4*)ew;
    int4 a = s4[0], b = s4[1], c = s4[2];
    float4 x = w4[0], y = w4[1], z = w4[2];
    float acc;
    acc  = x.x * Rc[a.x];  acc += x.y * Rc[a.y];
    acc += x.z * Rc[a.z];  acc += x.w * Rc[a.w];
    acc += y.x * Rc[b.x];  acc += y.y * Rc[b.y];
    acc += y.z * Rc[b.z];  acc += y.w * Rc[b.w];
    acc += z.x * Rc[c.x];  acc += z.y * Rc[c.y];
    acc += z.z * Rc[c.z];  acc += z.w * Rc[c.w];
    return acc;
}

__device__ __forceinline__ void scale_row(float* __restrict__ wout, int g, float r) {
    float4* w4 = (float4*)(wout + (size_t)g * DEG);
#pragma unroll
    for (int k = 0; k < DEG / 4; ++k) {
        float4 v = w4[k];
        v.x *= r; v.y *= r; v.z *= r; v.w *= r;
        w4[k] = v;
    }
}

// ===========================================================================
// FUSED v7. Prologue: softmax + E12 compaction (global partition, global
// barriers). Fast rounds: per-XCD redundant batch compute; R staged to LDS
// per 100 KB chunk via sc0 loads from local L2; edges consumed from a
// chunk-bucketed, block-uniform-padded, column-major stream (coalesced, no
// divergence, no range tests). No device-scope fences in the round loop.
// Slow path (flag-agreed at global barriers): E12 direct gathers + global
// barriers (R1-equivalent cost).
// ===========================================================================
__global__ __launch_bounds__(BLK, 4)
void fused7_k(const float* __restrict__ fp, const int* __restrict__ adj,
              const int* __restrict__ in_idx, const float* __restrict__ dem,
              const int* __restrict__ nn, float* __restrict__ wout,
              char* __restrict__ wsb, int nodes) {
    __shared__ float lds[LDSF];
    __shared__ int s_xcd, s_rank, s_mode, s_part, s_jbad;
    __shared__ int s_cm[4];
    __shared__ int s_off[5];

    unsigned* g_cnt  = (unsigned*)(wsb);
    unsigned* g_gen  = (unsigned*)(wsb + 128);
    unsigned* blkcnt = (unsigned*)(wsb + 2304);   // [8]
    unsigned* ovf    = (unsigned*)(wsb + 2432);
    unsigned* jovf   = (unsigned*)(wsb + 2436);
    int*   e_src   = (int*)(wsb + 4096);
    float* e_w     = (float*)(wsb + 4096 + (size_t)nodes * E12 * 4);
    float* Rf0     = (float*)((char*)e_w + (size_t)nodes * E12 * 4);
    float* Rf1     = Rf0 + nodes;
    float* slices  = Rf1 + nodes;                   // 16 x N floats
    uint2* regions = (uint2*)((char*)(slices) + (size_t)nodes * 16);

    const int N   = *nn;
    const int tid = (int)threadIdx.x;
    const int T   = (int)gridDim.x * BLK;
    const unsigned nblocks = gridDim.x;
    unsigned gb = 0;

    // ---- entry: self-organize ----
    if (tid == 0) {
        int x = get_xcd();
        s_xcd  = x;
        s_rank = (int)__hip_atomic_fetch_add(&blkcnt[x], 1u, __ATOMIC_RELAXED,
                                             __HIP_MEMORY_SCOPE_AGENT);
    }
    __syncthreads();
    const int my_xcd  = s_xcd;
    const int my_rank = s_rank;

    // ---- P0: softmax (global partition, 2 nodes/thread) ----
#pragma unroll
    for (int rep = 0; rep < 2; ++rep) {
        int g = (int)blockIdx.x * BLK + tid + rep * T;
        if (g < nodes) softmax_row(fp, adj, wout, (size_t)g * DEG, N);
    }
    grid_barrier(g_cnt, g_gen, ++gb, nblocks);

    // ---- P1: E12 compaction + validity checks (global partition) ----
#pragma unroll
    for (int rep = 0; rep < 2; ++rep) {
        int g = (int)blockIdx.x * BLK + tid + rep * T;
        if (g >= nodes) continue;
        const int gbat = g / N;
        const int4* t4 = (const int4*)(in_idx + (size_t)g * 48);
        int cb[16], cs[16], cl[16];
#pragma unroll
        for (int q = 0; q < 4; ++q) {
            int4 qa = t4[3*q + 0];
            int4 qb = t4[3*q + 1];
            int4 qc = t4[3*q + 2];
            cb[4*q+0] = qa.x; cs[4*q+0] = qa.y; cl[4*q+0] = qa.z;
            cb[4*q+1] = qa.w; cs[4*q+1] = qb.x; cl[4*q+1] = qb.y;
            cb[4*q+2] = qb.z; cs[4*q+2] = qb.w; cl[4*q+2] = qc.x;
            cb[4*q+3] = qc.y; cs[4*q+3] = qc.z; cl[4*q+3] = qc.w;
        }
        float cw[16];
#pragma unroll
        for (int k = 0; k < 16; ++k)
            cw[k] = wout[((size_t)cb[k] * N + cs[k]) * DEG + cl[k]];
        bool bad = (cw[12] != 0.f) || (cw[13] != 0.f) ||
                   (cw[14] != 0.f) || (cw[15] != 0.f);
#pragma unroll
        for (int k = 0; k < E12; ++k)
            bad = bad || (cb[k] != gbat) || ((unsigned)cs[k] >= (unsigned)N);
        if (bad) st_u32_sc0(ovf, 1u);
        int4*   es4 = (int4*)(e_src + (size_t)g * E12);
        float4* ew4 = (float4*)(e_w + (size_t)g * E12);
        es4[0] = make_int4(cs[0], cs[1], cs[2], cs[3]);     // batch-LOCAL srcs
        es4[1] = make_int4(cs[4], cs[5], cs[6], cs[7]);
        es4[2] = make_int4(cs[8], cs[9], cs[10], cs[11]);
        ew4[0] = make_float4(cw[0], cw[1], cw[2], cw[3]);
        ew4[1] = make_float4(cw[4], cw[5], cw[6], cw[7]);
        ew4[2] = make_float4(cw[8], cw[9], cw[10], cw[11]);
    }
    grid_barrier(g_cnt, g_gen, ++gb, nblocks);

    // ---- mode decision ----
    const int npb   = (N + 31) >> 5;                 // nodes per rank (32 ranks)
    const int nch   = (N + LDSF - 1) / LDSF;         // chunks
    const int chunk = (N + nch - 1) / nch;
    if (tid == 0) {
        unsigned cc[8];
#pragma unroll
        for (int x = 0; x < 8; ++x) cc[x] = ld_u32_sc0(&blkcnt[x]);
        bool ok = (4 * N == nodes) && (N > 0) && (npb <= 4 * BLK) &&
                  (nch >= 1) && (nch <= 4) && (chunk <= LDSF) &&
                  (ld_u32_sc0(ovf) == 0u);
#pragma unroll
        for (int p = 0; p < 4; ++p)
            ok = ok && (cc[2*p] >= 32u || cc[2*p+1] >= 32u);
        s_mode = ok ? 1 : 0;
        s_part = (ok && cc[my_xcd] >= 32u && my_rank < 32) ? 1 : 0;
    }
    __syncthreads();
    const bool fast = (s_mode == 1);
    const bool part = (s_part == 1);

    if (fast) {
        // ---- participant: build bucketed edge stream ----
        const int batch = my_xcd >> 1;
        const int lbase = my_rank * npb;
        const int lim   = min(lbase + npb, N);
        float d[4];
        int   lno[4];
        bool  act[4];
        float r[4];
        uint2* reg = regions + (size_t)(my_xcd * 32 + my_rank) * (JMAX * BLK);

        if (part) {
            if (tid < 4) s_cm[tid] = 0;
            __syncthreads();
            const int b1 = chunk, b2 = 2 * chunk, b3 = 3 * chunk;
            int c0 = 0, c1 = 0, c2 = 0, c3 = 0;
#pragma unroll
            for (int s = 0; s < 4; ++s) {
                int l = lbase + s * BLK + tid;
                lno[s] = l;
                act[s] = (l < lim);
                d[s] = 0.f;
                if (act[s]) {
                    int g = batch * N + l;
                    d[s] = dem[g];
                    const int* es = e_src + (size_t)g * E12;
#pragma unroll
                    for (int k = 0; k < E12; ++k) {
                        int src = es[k];
                        int c = (src >= b1) + (src >= b2) + (src >= b3);
                        c0 += (c == 0); c1 += (c == 1);
                        c2 += (c == 2); c3 += (c == 3);
                    }
                }
            }
            atomicMax(&s_cm[0], c0); atomicMax(&s_cm[1], c1);
            atomicMax(&s_cm[2], c2); atomicMax(&s_cm[3], c3);
            __syncthreads();
            if (tid == 0) {
                s_off[0] = 0;
                s_off[1] = s_cm[0];
                s_off[2] = s_cm[0] + s_cm[1];
                s_off[3] = s_cm[0] + s_cm[1] + s_cm[2];
                s_off[4] = s_cm[0] + s_cm[1] + s_cm[2] + s_cm[3];
                if (s_off[4] > JMAX) st_u32_sc0(jovf, 1u);
            }
            __syncthreads();
            if (s_off[4] <= JMAX) {
                int cur0 = s_off[0], cur1 = s_off[1],
                    cur2 = s_off[2], cur3 = s_off[3];
#pragma unroll
                for (int s = 0; s < 4; ++s) {
                    if (!act[s]) continue;
                    int g = batch * N + lno[s];
                    const int*   es = e_src + (size_t)g * E12;
                    const float* ew = e_w + (size_t)g * E12;
#pragma unroll
                    for (int k = 0; k < E12; ++k) {
                        int src = es[k];
                        float w = ew[k];
                        int c = (src >= b1) + (src >= b2) + (src >= b3);
                        int j = (c == 0) ? cur0 : (c == 1) ? cur1
                               : (c == 2) ? cur2 : cur3;
                        reg[(size_t)j * BLK + tid] =
                            make_uint2((unsigned)src | ((unsigned)s << 20),
                                       __float_as_uint(w));
                        cur0 += (c == 0); cur1 += (c == 1);
                        cur2 += (c == 2); cur3 += (c == 3);
                    }
                }
                // pad each bucket to block-uniform bounds (w=0 contributions)
                int curs[1];
                (void)curs;
                {
                    int cc_[4] = {cur0, cur1, cur2, cur3};
#pragma unroll
                    for (int c = 0; c < 4; ++c) {
                        unsigned ps = (unsigned)(c * chunk);
                        for (int j = cc_[c]; j < s_off[c + 1]; ++j)
                            reg[(size_t)j * BLK + tid] = make_uint2(ps, 0u);
                    }
                }
            }
        }
        grid_barrier(g_cnt, g_gen, ++gb, nblocks);   // agree on jovf
        if (tid == 0) s_jbad = (int)ld_u32_sc0(jovf);
        __syncthreads();

        if (s_jbad == 0) {
            if (!part) return;            // extra / deficient-XCD blocks exit
            // ---- fast rounds: XCD-local ----
            unsigned* xc = (unsigned*)(wsb + 256 + my_xcd * 256);
            unsigned* xg = (unsigned*)(wsb + 256 + my_xcd * 256 + 128);
            unsigned xb = 0;
            float* bufA = slices + (size_t)(2 * my_xcd + 0) * N;
            float* bufB = slices + (size_t)(2 * my_xcd + 1) * N;

#pragma unroll
            for (int s = 0; s < 4; ++s) {
                r[s] = fmaxf(-d[s], 0.f);
                if (act[s]) st_sc0(bufA + lno[s], r[s]);
            }
            xcd_barrier(xc, xg, ++xb, 32u);

            float* Rin  = bufA;
            float* Rout = bufB;
            for (int t = 1; t < MAX_ITERS; ++t) {
                float a0 = 0.f, a1 = 0.f, a2 = 0.f, a3 = 0.f;
                for (int c = 0; c < nch; ++c) {
                    const int cbase = c * chunk;
                    const int ce = min(chunk, N - cbase);
                    for (int i = tid; i < ce; i += BLK)
                        lds[i] = ld_sc0(Rin + cbase + i);
                    __syncthreads();
                    const int jb = s_off[c], je = s_off[c + 1];
                    for (int j = jb; j < je; ++j) {        // uniform bounds
                        uint2 pr = reg[(size_t)j * BLK + tid];
                        float w = __uint_as_float(pr.y);
                        int idx = (int)(pr.x & 0xFFFFFu) - cbase;
                        int tg  = (int)(pr.x >> 20);
                        float wv = w * lds[idx];
                        a0 += (tg == 0) ? wv : 0.f;
                        a1 += (tg == 1) ? wv : 0.f;
                        a2 += (tg == 2) ? wv : 0.f;
                        a3 += (tg == 3) ? wv : 0.f;
                    }
                    __syncthreads();
                }
                r[0] = fmaxf(a0 - d[0], 0.f);
                r[1] = fmaxf(a1 - d[1], 0.f);
                r[2] = fmaxf(a2 - d[2], 0.f);
                r[3] = fmaxf(a3 - d[3], 0.f);
                if (t < MAX_ITERS - 1) {
#pragma unroll
                    for (int s = 0; s < 4; ++s)
                        if (act[s]) st_sc0(Rout + lno[s], r[s]);
                    xcd_barrier(xc, xg, ++xb, 32u);
                    float* tmp = Rin; Rin = Rout; Rout = tmp;
                }
            }
#pragma unroll
            for (int s = 0; s < 4; ++s)
                if (act[s]) scale_row(wout, batch * N + lno[s], r[s]);
            return;
        }
        // fall through to slow rounds (all blocks; j-budget overflow)
    }

    // ---- SLOW rounds: E12 direct gathers + global barriers ----
    {
        int g0 = (int)blockIdx.x * BLK + tid;
        int g1 = g0 + T;
        bool a0 = (g0 < nodes), a1 = (g1 < nodes);
        float d0 = a0 ? dem[g0] : 0.f;
        float d1 = a1 ? dem[g1] : 0.f;
        int base0 = a0 ? (g0 / N) * N : 0;
        int base1 = a1 ? (g1 / N) * N : 0;
        float r0 = fmaxf(-d0, 0.f), r1 = fmaxf(-d1, 0.f);
        if (a0) Rf0[g0] = r0;
        if (a1) Rf0[g1] = r1;
        grid_barrier(g_cnt, g_gen, ++gb, nblocks);
        const float* Rc = Rf0;
        float*       Rn = Rf1;
        for (int t = 1; t < MAX_ITERS; ++t) {
            if (a0) r0 = fmaxf(node_acc12(e_src + (size_t)g0 * E12,
                                          e_w + (size_t)g0 * E12,
                                          Rc + base0) - d0, 0.f);
            if (a1) r1 = fmaxf(node_acc12(e_src + (size_t)g1 * E12,
                                          e_w + (size_t)g1 * E12,
                                          Rc + base1) - d1, 0.f);
            if (t < MAX_ITERS - 1) {
                if (a0) Rn[g0] = r0;
                if (a1) Rn[g1] = r1;
                grid_barrier(g_cnt, g_gen, ++gb, nblocks);
                float* tmp = (float*)Rc; Rc = Rn; Rn = tmp;
            }
        }
        if (a0) scale_row(wout, g0, r0);
        if (a1) scale_row(wout, g1, r1);
    }
}

// ===========================================================================
// HOST FALLBACK (round-1 kernels, known-correct)
// ===========================================================================
__global__ void softmax_k(const float* __restrict__ fp, const int* __restrict__ adj,
                          const int* __restrict__ nn, float* __restrict__ wout,
                          int nodes) {
    int i = blockIdx.x * blockDim.x + threadIdx.x;
    if (i >= nodes) return;
    softmax_row(fp, adj, wout, (size_t)i * DEG, *nn);
}

__global__ void gather_k(const int* __restrict__ in_idx, const float* __restrict__ w,
                         const int* __restrict__ nn, int* __restrict__ e_srcO,
                         float* __restrict__ e_wO, int edges) {
    int e = blockIdx.x * blockDim.x + threadIdx.x;
    if (e >= edges) return;
    const int N = *nn;
    size_t e3 = 3 * (size_t)e;
    int fi = in_idx[e3] * N + in_idx[e3 + 1];
    e_srcO[e] = fi;
    e_wO[e]   = w[(size_t)fi * DEG + in_idx[e3 + 2]];
}

__global__ void iter_k(const int* __restrict__ e_srcO, const float* __restrict__ e_wO,
                       const float* __restrict__ dem, const float* __restrict__ Rin,
                       float* __restrict__ Rout, int nodes) {
    int i = blockIdx.x * blockDim.x + threadIdx.x;
    if (i >= nodes) return;
    const size_t base = (size_t)i * DEG;
    const int4*   s4 = (const int4*)(e_srcO + base);
    const float4* w4 = (const float4*)(e_wO + base);
    float acc = 0.f;
#pragma unroll
    for (int k = 0; k < DEG / 4; ++k) {
        int4   s = s4[k];
        float4 w = w4[k];
        acc += w.x * Rin[s.x];
        acc += w.y * Rin[s.y];
        acc += w.z * Rin[s.z];
        acc += w.w * Rin[s.w];
    }
    float r = acc - dem[i];
    Rout[i] = r > 0.f ? r : 0.f;
}

__global__ void final_k(const float* __restrict__ w, const float* __restrict__ R,
                        float* __restrict__ out, int nodes) {
    int i = blockIdx.x * blockDim.x + threadIdx.x;
    if (i >= nodes) return;
    scale_row((float*)w, i, R[i]);
    (void)out;
}

extern "C" void kernel_launch(void* const* d_in, const int* in_sizes, int n_in,
                              void* d_out, int out_size, void* d_ws, size_t ws_size,
                              hipStream_t stream) {
    const float* fp  = (const float*)d_in[0];
    const float* dem = (const float*)d_in[1];
    const int*   adj = (const int*)d_in[2];
    const int*   idx = (const int*)d_in[3];
    const int*   nn  = (const int*)d_in[4];

    const int edges = in_sizes[0];   // B*N*D
    const int nodes = in_sizes[1];   // B*N

    float* weights = (float*)d_out;
    char*  ws      = (char*)d_ws;

    int dev = 0, cus = 0, maxBlk = 0;
    hipGetDevice(&dev);
    hipDeviceGetAttribute(&cus, hipDeviceAttributeMultiprocessorCount, dev);
    hipOccupancyMaxActiveBlocksPerMultiprocessor(&maxBlk, (const void*)fused7_k,
                                                 BLK, 0);

    // ws layout: 4096 | e_src 12n*4 | e_w 12n*4 | Rf 2n*4 | slices 16n | regions
    const size_t need = 4096 + (size_t)nodes * (E12 * 8 + 8 + 16)
                      + (size_t)256 * JMAX * BLK * 8;
    const int grid = cus;

    const bool fused_ok = (maxBlk >= 1) && (cus >= 16) &&
                          ((long long)grid * BLK * 2 >= nodes) &&
                          (ws_size >= need) && (nodes % 4 == 0);

    if (fused_ok) {
        hipMemsetAsync(ws, 0, 4096, stream);
        void* args[] = { (void*)&fp, (void*)&adj, (void*)&idx, (void*)&dem,
                         (void*)&nn, (void*)&weights, (void*)&ws, (void*)&nodes };
        hipLaunchCooperativeKernel((const void*)fused7_k, dim3(grid), dim3(BLK),
                                   args, 0, stream);
    } else {
        int*   e_srcO = (int*)ws;
        float* e_wO   = (float*)(ws + (size_t)edges * sizeof(int));
        float* R0     = (float*)(ws + (size_t)edges * 8);
        float* R1     = R0 + nodes;
        const int blk = 256;
        const int gn = (nodes + blk - 1) / blk;
        const int ge = (edges + blk - 1) / blk;
        hipMemsetAsync(R0, 0, (size_t)nodes * sizeof(float), stream);
        softmax_k<<<gn, blk, 0, stream>>>(fp, adj, nn, weights, nodes);
        gather_k<<<ge, blk, 0, stream>>>(idx, weights, nn, e_srcO, e_wO, edges);
        float* a = R0;
        float* b = R1;
        for (int t = 0; t < MAX_ITERS; ++t) {
            iter_k<<<gn, blk, 0, stream>>>(e_srcO, e_wO, dem, a, b, nodes);
            float* tmp = a; a = b; b = tmp;
        }
        final_k<<<gn, blk, 0, stream>>>(weights, a, (float*)d_out, nodes);
    }
}